// Round 1
// 372.284 us; speedup vs baseline: 1.0132x; 1.0132x over previous
//
#include <hip/hip_runtime.h>

// SplitLinear: out[b, o*C + c] = sum_s x[b, s*C + c] * w[o, s, c] + bias[o*C + c]
// x: [64, 1e6] fp32, w: [4, 400, 2500] fp32, bias: [10000], out: [64, 10000]
//
// R7 theory: problem is purely HBM-bound (512 MFLOP = 3.3 us VALU; ~295 MB
// min traffic = ~47 us @ 6.3 TB/s). Prior structures all mapped 256-thr
// blocks to 4 KB sub-windows of each 10 KB s-row -> strided 4-of-10 KB
// bursts -> ~50% DRAM row-buffer efficiency -> 2.5-3.5 TB/s plateau, while
// harness fills hit 6.7 TB/s on contiguous streams.
// Fix: 640-thread blocks (10 waves) span ALL 625 c-quads of an s-row, so
// every stream (2 x-rows + 4 w-sets) is FULLY contiguous in 10 KB steps —
// same shape as the 6.7 TB/s fill. NSPLIT 16->8 halves ws round-trip;
// z = blockIdx.x puts one 2 MB w-slice per XCD L2 (wg%8 heuristic).
// Grid (8,32) = 256 blocks = 1/CU; 84 KB LDS pad forces 1 block/CU.

constexpr int IN_F   = 1000000;
constexpr int S_DIM  = 400;
constexpr int C_DIM  = 2500;
constexpr int O_SETS = 4;
constexpr int B_SZ   = 64;
constexpr int OC     = O_SETS * C_DIM;    // 10000
constexpr int OUT_N  = B_SZ * OC;         // 640000

constexpr int NQ      = C_DIM / 4;        // 625 float4 quads per s-row
constexpr int THREADS = 640;              // 10 waves, covers one full s-row
constexpr int NSPLIT  = 8;                // s segments, one per XCD
constexpr int SSEG    = S_DIM / NSPLIT;   // 50 s-steps per segment
constexpr int BT      = 2;                // b rows per thread
constexpr int BGRP    = B_SZ / BT;        // 32
constexpr int STEPQ   = NQ;               // float4 stride per s-step (contig!)

constexpr size_t WS_NEED = (size_t)NSPLIT * OUT_N * sizeof(float);  // 20.5 MB

__device__ __forceinline__ void fma4(float4& a, const float4& p, const float4& q) {
    a.x = fmaf(p.x, q.x, a.x);
    a.y = fmaf(p.y, q.y, a.y);
    a.z = fmaf(p.z, q.z, a.z);
    a.w = fmaf(p.w, q.w, a.w);
}

// ---------------- Main path ----------------

// grid (NSPLIT, BGRP), block = 640 thr. Thread tid -> c-quad tid (block spans
// one complete 10 KB s-row); BT=2 b-rows, 4 o-sets, acc over SSEG=50 s-steps.
// All 6 streams per block advance contiguously by 10 KB/step.
__global__ __launch_bounds__(THREADS, 3) void sl_part(const float* __restrict__ x,
                                                      const float* __restrict__ w,
                                                      float* __restrict__ ws) {
    // 84 KB pad: caps residency at 1 block/CU so the 256-block grid spreads
    // 1 block per CU even under greedy dispatch. Reference is never executed
    // (x != nullptr at runtime) but is unprovable, so the LDS stays allocated.
    __shared__ float lds_pad[21504];
    if ((size_t)x == 0) lds_pad[threadIdx.x] = 1.f;

    const int tid = threadIdx.x;
    const bool act = (tid < NQ);
    const int q   = act ? tid : NQ - 1;   // clamp: junk loads stay in-bounds
    const int z   = blockIdx.x;           // wg%8 -> z  => one w-slice per XCD
    const int b0  = blockIdx.y * BT;
    const int s0  = z * SSEG;

    const float4* xp[BT];
#pragma unroll
    for (int i = 0; i < BT; ++i)
        xp[i] = (const float4*)(x + (size_t)(b0 + i) * IN_F + (size_t)s0 * C_DIM) + q;

    const float4* wp[O_SETS];
#pragma unroll
    for (int o = 0; o < O_SETS; ++o)
        wp[o] = (const float4*)(w + (size_t)o * (S_DIM * C_DIM) + (size_t)s0 * C_DIM) + q;

    float4 acc[BT][O_SETS];
#pragma unroll
    for (int i = 0; i < BT; ++i)
#pragma unroll
        for (int o = 0; o < O_SETS; ++o)
            acc[i][o] = make_float4(0.f, 0.f, 0.f, 0.f);

    // Ping-pong register prefetch: 6 loads in flight while 32 fma run.
    float4 xb[2][BT], wb[2][O_SETS];
#pragma unroll
    for (int i = 0; i < BT; ++i) { xb[0][i] = *xp[i]; xp[i] += STEPQ; }
#pragma unroll
    for (int o = 0; o < O_SETS; ++o) { wb[0][o] = *wp[o]; wp[o] += STEPQ; }

#pragma unroll
    for (int s = 0; s < SSEG; ++s) {
        const int cur = s & 1, nxt = cur ^ 1;
        if (s + 1 < SSEG) {   // compile-time after full unroll
#pragma unroll
            for (int i = 0; i < BT; ++i) { xb[nxt][i] = *xp[i]; xp[i] += STEPQ; }
#pragma unroll
            for (int o = 0; o < O_SETS; ++o) { wb[nxt][o] = *wp[o]; wp[o] += STEPQ; }
        }
#pragma unroll
        for (int i = 0; i < BT; ++i)
#pragma unroll
            for (int o = 0; o < O_SETS; ++o)
                fma4(acc[i][o], xb[cur][i], wb[cur][o]);
    }

    if (act) {
        float* base = ws + (size_t)z * OUT_N;
#pragma unroll
        for (int i = 0; i < BT; ++i) {
            float* orow = base + (size_t)(b0 + i) * OC;
#pragma unroll
            for (int o = 0; o < O_SETS; ++o)
                *(float4*)(orow + o * C_DIM + q * 4) = acc[i][o];   // 10 KB contig/(i,o)
        }
    }
}

// out[idx] = bias[idx % OC] + sum_z ws[z][idx]
__global__ __launch_bounds__(256) void sl_reduce(const float* __restrict__ ws,
                                                 const float* __restrict__ bias,
                                                 float* __restrict__ out) {
    const int t = blockIdx.x * 256 + threadIdx.x;
    if (t >= OUT_N / 4) return;
    const int idx = t * 4;
    const int oc  = idx % OC;   // OC % 4 == 0 -> a float4 never crosses rows

    float4 s0 = *(const float4*)(bias + oc);
    float4 s1 = make_float4(0.f, 0.f, 0.f, 0.f);
#pragma unroll
    for (int z = 0; z < NSPLIT; z += 2) {
        float4 v0 = *(const float4*)(ws + (size_t)z * OUT_N + idx);
        float4 v1 = *(const float4*)(ws + (size_t)(z + 1) * OUT_N + idx);
        s0.x += v0.x; s0.y += v0.y; s0.z += v0.z; s0.w += v0.w;
        s1.x += v1.x; s1.y += v1.y; s1.z += v1.z; s1.w += v1.w;
    }
    s0.x += s1.x; s0.y += s1.y; s0.z += s1.z; s0.w += s1.w;
    *(float4*)(out + idx) = s0;
}

// ---------------- Fallback (ws too small): atomics ----------------

__global__ __launch_bounds__(256) void sl_init(const float* __restrict__ bias,
                                               float* __restrict__ out) {
    int j = blockIdx.x * 256 + threadIdx.x;
    if (j < OC) out[(size_t)blockIdx.y * OC + j] = bias[j];
}

__global__ __launch_bounds__(64) void sl_atomic(const float* __restrict__ x,
                                                const float* __restrict__ w,
                                                float* __restrict__ out) {
    const int lane = threadIdx.x;
    const int q    = blockIdx.x * 64 + lane;
    if (q >= NQ) return;
    const int b  = blockIdx.y;
    const int s0 = blockIdx.z * SSEG;

    const float4* xp = (const float4*)(x + (size_t)b * IN_F + (size_t)s0 * C_DIM) + q;
    const float4* wp[O_SETS];
#pragma unroll
    for (int o = 0; o < O_SETS; ++o)
        wp[o] = (const float4*)(w + (size_t)o * (S_DIM * C_DIM) + (size_t)s0 * C_DIM) + q;

    float4 acc[O_SETS];
#pragma unroll
    for (int o = 0; o < O_SETS; ++o) acc[o] = make_float4(0.f, 0.f, 0.f, 0.f);

    for (int s = 0; s < SSEG; ++s) {
        float4 xv = *xp; xp += STEPQ;
        float4 wv4[O_SETS];
#pragma unroll
        for (int o = 0; o < O_SETS; ++o) { wv4[o] = *wp[o]; wp[o] += STEPQ; }
#pragma unroll
        for (int o = 0; o < O_SETS; ++o) fma4(acc[o], xv, wv4[o]);
    }

    float* orow = out + (size_t)b * OC;
#pragma unroll
    for (int o = 0; o < O_SETS; ++o) {
        float* dst = orow + o * C_DIM + q * 4;
        atomicAdd(dst + 0, acc[o].x);
        atomicAdd(dst + 1, acc[o].y);
        atomicAdd(dst + 2, acc[o].z);
        atomicAdd(dst + 3, acc[o].w);
    }
}

extern "C" void kernel_launch(void* const* d_in, const int* in_sizes, int n_in,
                              void* d_out, int out_size, void* d_ws, size_t ws_size,
                              hipStream_t stream) {
    const float* x    = (const float*)d_in[0];
    const float* wgt  = (const float*)d_in[1];
    const float* bias = (const float*)d_in[2];
    float* out = (float*)d_out;

    if (ws_size >= WS_NEED) {
        float* ws = (float*)d_ws;
        dim3 g(NSPLIT, BGRP);
        sl_part<<<g, THREADS, 0, stream>>>(x, wgt, ws);
        sl_reduce<<<(OUT_N / 4 + 255) / 256, 256, 0, stream>>>(ws, bias, out);
    } else {
        dim3 gInit((OC + 255) / 256, B_SZ);
        sl_init<<<gInit, 256, 0, stream>>>(bias, out);
        dim3 g((NQ + 63) / 64, B_SZ, NSPLIT);
        sl_atomic<<<g, 64, 0, stream>>>(x, wgt, out);
    }
}

// Round 2
// 366.652 us; speedup vs baseline: 1.0287x; 1.0154x over previous
//
#include <hip/hip_runtime.h>

// SplitLinear: out[b, o*C + c] = sum_s x[b, s*C + c] * w[o, s, c] + bias[o*C + c]
// x: [64, 1e6] fp32, w: [4, 400, 2500] fp32, bias: [10000], out: [64, 10000]
//
// R8 theory: R7's full-row contiguity (640-thr blocks, 10 KB steps) moved
// nothing (-5 us = exactly the ws-traffic halving) => burst size was NOT the
// limiter. sl_part < 152 us (never appears above the harness fills in the
// top-5). Two remaining suspects:
//  (1) L2 pollution: per XCD, the 2 MB shared w slice is thrashed by 32 MB
//      of use-once x flowing through the same 4 MB L2 (block drift in s >
//      w-line reuse window) -> w re-fetched from HBM many times.
//      Fix: NONTEMPORAL loads for x, nt stores for ws/out; w stays temporal.
//  (2) Shallow MLP: ping-pong = only 6 loads (6 KB) in flight per wave;
//      congested load latency >> 900 cyc caps the read stream (Little's law).
//      Fix: depth-3 rotation (load s+2 while computing s) = 12 KB/wave in
//      flight; drop the 1-block/CU LDS pad (capping residency was backwards
//      for a latency-bound read stream).

constexpr int IN_F   = 1000000;
constexpr int S_DIM  = 400;
constexpr int C_DIM  = 2500;
constexpr int O_SETS = 4;
constexpr int B_SZ   = 64;
constexpr int OC     = O_SETS * C_DIM;    // 10000
constexpr int OUT_N  = B_SZ * OC;         // 640000

constexpr int NQ      = C_DIM / 4;        // 625 float4 quads per s-row
constexpr int THREADS = 640;              // 10 waves, covers one full s-row
constexpr int NSPLIT  = 8;                // s segments, one per XCD
constexpr int SSEG    = S_DIM / NSPLIT;   // 50 s-steps per segment
constexpr int BT      = 2;                // b rows per thread
constexpr int BGRP    = B_SZ / BT;        // 32
constexpr int STEPQ   = NQ;               // float4 stride per s-step (contig)

constexpr size_t WS_NEED = (size_t)NSPLIT * OUT_N * sizeof(float);  // 20.5 MB

typedef float f4 __attribute__((ext_vector_type(4)));

__device__ __forceinline__ f4 ntload(const f4* p) {
    return __builtin_nontemporal_load(p);
}

__device__ __forceinline__ void fma4(f4& a, f4 p, f4 q) {
    a.x = fmaf(p.x, q.x, a.x);
    a.y = fmaf(p.y, q.y, a.y);
    a.z = fmaf(p.z, q.z, a.z);
    a.w = fmaf(p.w, q.w, a.w);
}

// ---------------- Main path ----------------

// grid (NSPLIT, BGRP), block = 640 thr. Thread tid -> c-quad tid (block spans
// one complete 10 KB s-row); BT=2 b-rows, 4 o-sets, acc over SSEG=50 s-steps.
// z = blockIdx.x -> wg%8 -> one 2 MB w-slice per XCD L2.
__global__ __launch_bounds__(THREADS, 3) void sl_part(const float* __restrict__ x,
                                                      const float* __restrict__ w,
                                                      float* __restrict__ ws) {
    const int tid = threadIdx.x;
    const bool act = (tid < NQ);
    const int q   = act ? tid : NQ - 1;   // clamp: junk loads stay in-bounds
    const int z   = blockIdx.x;
    const int b0  = blockIdx.y * BT;
    const int s0  = z * SSEG;

    const f4* xp[BT];
#pragma unroll
    for (int i = 0; i < BT; ++i)
        xp[i] = (const f4*)(x + (size_t)(b0 + i) * IN_F + (size_t)s0 * C_DIM) + q;

    const f4* wp[O_SETS];
#pragma unroll
    for (int o = 0; o < O_SETS; ++o)
        wp[o] = (const f4*)(w + (size_t)o * (S_DIM * C_DIM) + (size_t)s0 * C_DIM) + q;

    f4 acc[BT][O_SETS];
#pragma unroll
    for (int i = 0; i < BT; ++i)
#pragma unroll
        for (int o = 0; o < O_SETS; ++o)
            acc[i][o] = (f4)(0.f);

    // Depth-3 rotation: 12 loads (12 KB/wave) in flight while 32 fma run.
    // All indices compile-time after full unroll (rule: no runtime-indexed
    // register arrays).
    f4 xb[3][BT], wb[3][O_SETS];
#pragma unroll
    for (int p = 0; p < 2; ++p) {
#pragma unroll
        for (int i = 0; i < BT; ++i) { xb[p][i] = ntload(xp[i]); xp[i] += STEPQ; }
#pragma unroll
        for (int o = 0; o < O_SETS; ++o) { wb[p][o] = *wp[o]; wp[o] += STEPQ; }
    }

#pragma unroll
    for (int s = 0; s < SSEG; ++s) {
        const int cur = s % 3;
        const int nxt = (s + 2) % 3;
        if (s + 2 < SSEG) {   // compile-time after full unroll
#pragma unroll
            for (int i = 0; i < BT; ++i) { xb[nxt][i] = ntload(xp[i]); xp[i] += STEPQ; }
#pragma unroll
            for (int o = 0; o < O_SETS; ++o) { wb[nxt][o] = *wp[o]; wp[o] += STEPQ; }
        }
#pragma unroll
        for (int i = 0; i < BT; ++i)
#pragma unroll
            for (int o = 0; o < O_SETS; ++o)
                fma4(acc[i][o], xb[cur][i], wb[cur][o]);
    }

    if (act) {
        float* base = ws + (size_t)z * OUT_N;
#pragma unroll
        for (int i = 0; i < BT; ++i) {
            float* orow = base + (size_t)(b0 + i) * OC;
#pragma unroll
            for (int o = 0; o < O_SETS; ++o)
                __builtin_nontemporal_store(acc[i][o],
                                            (f4*)(orow + o * C_DIM + q * 4));
        }
    }
}

// out[idx] = bias[idx % OC] + sum_z ws[z][idx]
__global__ __launch_bounds__(256) void sl_reduce(const float* __restrict__ ws,
                                                 const float* __restrict__ bias,
                                                 float* __restrict__ out) {
    const int t = blockIdx.x * 256 + threadIdx.x;
    if (t >= OUT_N / 4) return;
    const int idx = t * 4;
    const int oc  = idx % OC;   // OC % 4 == 0 -> a float4 never crosses rows

    f4 s0 = *(const f4*)(bias + oc);
    f4 s1 = (f4)(0.f);
#pragma unroll
    for (int z = 0; z < NSPLIT; z += 2) {
        f4 v0 = ntload((const f4*)(ws + (size_t)z * OUT_N + idx));
        f4 v1 = ntload((const f4*)(ws + (size_t)(z + 1) * OUT_N + idx));
        s0.x += v0.x; s0.y += v0.y; s0.z += v0.z; s0.w += v0.w;
        s1.x += v1.x; s1.y += v1.y; s1.z += v1.z; s1.w += v1.w;
    }
    s0.x += s1.x; s0.y += s1.y; s0.z += s1.z; s0.w += s1.w;
    __builtin_nontemporal_store(s0, (f4*)(out + idx));
}

// ---------------- Fallback (ws too small): atomics ----------------

__global__ __launch_bounds__(256) void sl_init(const float* __restrict__ bias,
                                               float* __restrict__ out) {
    int j = blockIdx.x * 256 + threadIdx.x;
    if (j < OC) out[(size_t)blockIdx.y * OC + j] = bias[j];
}

__global__ __launch_bounds__(64) void sl_atomic(const float* __restrict__ x,
                                                const float* __restrict__ w,
                                                float* __restrict__ out) {
    const int lane = threadIdx.x;
    const int qq   = blockIdx.x * 64 + lane;
    if (qq >= NQ) return;
    const int b  = blockIdx.y;
    const int s0 = blockIdx.z * SSEG;

    const f4* xp = (const f4*)(x + (size_t)b * IN_F + (size_t)s0 * C_DIM) + qq;
    const f4* wp[O_SETS];
#pragma unroll
    for (int o = 0; o < O_SETS; ++o)
        wp[o] = (const f4*)(w + (size_t)o * (S_DIM * C_DIM) + (size_t)s0 * C_DIM) + qq;

    f4 acc[O_SETS];
#pragma unroll
    for (int o = 0; o < O_SETS; ++o) acc[o] = (f4)(0.f);

    for (int s = 0; s < SSEG; ++s) {
        f4 xv = *xp; xp += STEPQ;
        f4 wv4[O_SETS];
#pragma unroll
        for (int o = 0; o < O_SETS; ++o) { wv4[o] = *wp[o]; wp[o] += STEPQ; }
#pragma unroll
        for (int o = 0; o < O_SETS; ++o) fma4(acc[o], xv, wv4[o]);
    }

    float* orow = out + (size_t)b * OC;
#pragma unroll
    for (int o = 0; o < O_SETS; ++o) {
        float* dst = orow + o * C_DIM + qq * 4;
        atomicAdd(dst + 0, acc[o].x);
        atomicAdd(dst + 1, acc[o].y);
        atomicAdd(dst + 2, acc[o].z);
        atomicAdd(dst + 3, acc[o].w);
    }
}

extern "C" void kernel_launch(void* const* d_in, const int* in_sizes, int n_in,
                              void* d_out, int out_size, void* d_ws, size_t ws_size,
                              hipStream_t stream) {
    const float* x    = (const float*)d_in[0];
    const float* wgt  = (const float*)d_in[1];
    const float* bias = (const float*)d_in[2];
    float* out = (float*)d_out;

    if (ws_size >= WS_NEED) {
        float* ws = (float*)d_ws;
        dim3 g(NSPLIT, BGRP);
        sl_part<<<g, THREADS, 0, stream>>>(x, wgt, ws);
        sl_reduce<<<(OUT_N / 4 + 255) / 256, 256, 0, stream>>>(ws, bias, out);
    } else {
        dim3 gInit((OC + 255) / 256, B_SZ);
        sl_init<<<gInit, 256, 0, stream>>>(bias, out);
        dim3 g((NQ + 63) / 64, B_SZ, NSPLIT);
        sl_atomic<<<g, 64, 0, stream>>>(x, wgt, out);
    }
}